// Round 4
// baseline (321.343 us; speedup 1.0000x reference)
//
#include <hip/hip_runtime.h>
#include <hip/hip_cooperative_groups.h>

namespace cg = cooperative_groups;

#define NN 256
#define DIN 32
#define DD 64
#define D2 128
#define RTOT 4096      // BB*NN rows
#define GB 256         // grid blocks (1 per CU)
#define RPB 16         // rows per block
#define JC 64          // j-chunk for agg

struct Params {
  const float *fea, *adj, *encW, *encb, *bondW, *eps, *W1, *b1, *g1, *be1,
              *W2, *b2, *gbn, *bbn;
  float *out, *x, *h1, *p1s, *p1q, *p2s, *p2q;
};

__device__ __forceinline__ void fma4(float4& o, float s, const float4& w) {
  o.x = fmaf(s, w.x, o.x);
  o.y = fmaf(s, w.y, o.y);
  o.z = fmaf(s, w.z, o.z);
  o.w = fmaf(s, w.w, o.w);
}

// LDS overlay (floats):
// bc : sW1[0,8192) sy[8192,12288) sadj[12288,13312) sh[13312,14336)
//      sbw[14336,14400) sS2[14400,14464) sB2[14464,14528) sred[14528,14784)
// d  : sW2[0,8192) sh1[8192,10304) sS[10304,10432) sB[10432,10560)
//      sredD[10560,10816) pstat[10816,12864)
__global__ __launch_bounds__(256) void fused(Params p) {
  cg::grid_group grid = cg::this_grid();
  __shared__ float smem[14784];
  const int tid = threadIdx.x, bid = blockIdx.x;
  const int lane = tid & 63, wv = tid >> 6;
  const int b = bid >> 4;            // batch
  const int r0 = (bid & 15) * RPB;   // row offset within batch

  // ---------------- enc: x = fea @ encW + encb ----------------
  {
#pragma unroll
    for (int k = 0; k < 4; ++k) {
      int g = bid * 1024 + k * 256 + tid;
      int r = g >> 6, c = g & 63;
      const float* fr = p.fea + r * DIN;
      float acc = p.encb[c];
#pragma unroll
      for (int kk = 0; kk < DIN; ++kk) acc = fmaf(fr[kk], p.encW[kk * DD + c], acc);
      p.x[g] = acc;
    }
  }
  grid.sync();

  for (int l = 0; l < 3; ++l) {
    // ================= bc phase: agg + h + MLP1 -> h1, p1 =================
    {
      float* sW1 = smem;
      float* sy  = smem + 8192;
      float* sadj = smem + 12288;
      float* sh  = smem + 13312;
      float* sbw = smem + 14336;
      float* sS2 = smem + 14400;
      float* sB2 = smem + 14464;
      float* sred = smem + 14528;

      for (int i = tid; i < DD * D2; i += 256) sW1[i] = p.W1[l * DD * D2 + i];
      if (tid < DD) sbw[tid] = p.bondW[l * DD + tid];
      if (l > 0) {
        // previous layer's BN2 affine from p2 partial stats
        int c = tid & 63, st = (tid >> 6) & 1, hf = tid >> 7;
        const float* pp = st ? p.p2q : p.p2s;
        const float4* p4 = (const float4*)(pp + c * GB + hf * 128);
        float s = 0.f;
#pragma unroll 8
        for (int g = 0; g < 32; ++g) { float4 v4 = p4[g]; s += v4.x + v4.y + v4.z + v4.w; }
        sred[tid] = s;
        __syncthreads();
        if (tid < 64) {
          float s1 = sred[tid] + sred[128 + tid];
          float q1 = sred[64 + tid] + sred[192 + tid];
          float mean = s1 * (1.f / RTOT);
          float var = fmaf(-mean, mean, q1 * (1.f / RTOT));
          float sc = p.gbn[(l - 1) * DD + tid] * rsqrtf(var + 1e-5f);
          sS2[tid] = sc;
          sB2[tid] = fmaf(-mean, sc, p.bbn[(l - 1) * DD + tid]);
        }
      }

      float acc[4] = {0.f, 0.f, 0.f, 0.f};
      const float* xsrc = p.x + (size_t)b * NN * DD;
      const float* adjb = p.adj + ((size_t)b * NN + r0) * NN;

      for (int jc = 0; jc < NN; jc += JC) {
        __syncthreads();   // protects sy/sadj reuse; first iter fences staging above
        // stage y[j][d] = relu(xval + bw), xval = (l? relu(affine(h2)) : x)
        const float4* src4 = (const float4*)(xsrc + jc * DD);
        for (int i = tid; i < JC * DD / 4; i += 256) {
          float4 v = src4[i];
          int d0 = (i & 15) * 4;
          if (l > 0) {
            v.x = fmaxf(fmaf(v.x, sS2[d0 + 0], sB2[d0 + 0]), 0.f);
            v.y = fmaxf(fmaf(v.y, sS2[d0 + 1], sB2[d0 + 1]), 0.f);
            v.z = fmaxf(fmaf(v.z, sS2[d0 + 2], sB2[d0 + 2]), 0.f);
            v.w = fmaxf(fmaf(v.w, sS2[d0 + 3], sB2[d0 + 3]), 0.f);
          }
          v.x = fmaxf(v.x + sbw[d0 + 0], 0.f);
          v.y = fmaxf(v.y + sbw[d0 + 1], 0.f);
          v.z = fmaxf(v.z + sbw[d0 + 2], 0.f);
          v.w = fmaxf(v.w + sbw[d0 + 3], 0.f);
          ((float4*)sy)[i] = v;
        }
        {
          int lr = tid >> 4, c4 = (tid & 15) * 4;
          *(float4*)&sadj[lr * JC + c4] =
              *(const float4*)(adjb + (size_t)lr * NN + jc + c4);
        }
        __syncthreads();
        // ballot-compacted accumulate, 8 independent LDS loads per wait
        unsigned long long m[4];
#pragma unroll
        for (int k = 0; k < 4; ++k)
          m[k] = __ballot(sadj[(wv * 4 + k) * JC + lane] != 0.f);
        while (m[0] | m[1] | m[2] | m[3]) {
          float v[8];
          bool hb[8];
#pragma unroll
          for (int k = 0; k < 4; ++k) {
            bool b0 = m[k] != 0ull;
            int j0 = b0 ? __builtin_ctzll(m[k]) : 0;
            m[k] &= m[k] - 1;
            bool b1 = m[k] != 0ull;
            int j1 = b1 ? __builtin_ctzll(m[k]) : 0;
            m[k] &= m[k] - 1;
            hb[2 * k] = b0; hb[2 * k + 1] = b1;
            v[2 * k] = sy[j0 * DD + lane];
            v[2 * k + 1] = sy[j1 * DD + lane];
          }
#pragma unroll
          for (int k = 0; k < 4; ++k)
            acc[k] += (hb[2 * k] ? v[2 * k] : 0.f) + (hb[2 * k + 1] ? v[2 * k + 1] : 0.f);
        }
      }

      float epv = 1.f + p.eps[l];
#pragma unroll
      for (int k = 0; k < 4; ++k) {
        int lr = wv * 4 + k;
        float raw = p.x[((size_t)b * NN + r0 + lr) * DD + lane];
        float xv = (l == 0) ? raw : fmaxf(fmaf(raw, sS2[lane], sB2[lane]), 0.f);
        sh[lr * DD + lane] = fmaf(epv, xv, acc[k]);
      }
      __syncthreads();

      // MLP1: 16x128 tile, thread = 2 rows x 4 cols
      int rg = tid >> 5, c0 = (tid & 31) * 4;
      float4 bv = *(const float4*)&p.b1[l * D2 + c0];
      float4 o0 = bv, o1 = bv;
      for (int d = 0; d < DD; d += 4) {
        float4 s0 = *(const float4*)&sh[(rg * 2 + 0) * DD + d];
        float4 s1 = *(const float4*)&sh[(rg * 2 + 1) * DD + d];
        float4 w0 = *(const float4*)&sW1[(d + 0) * D2 + c0];
        float4 w1 = *(const float4*)&sW1[(d + 1) * D2 + c0];
        float4 w2 = *(const float4*)&sW1[(d + 2) * D2 + c0];
        float4 w3 = *(const float4*)&sW1[(d + 3) * D2 + c0];
        fma4(o0, s0.x, w0); fma4(o0, s0.y, w1); fma4(o0, s0.z, w2); fma4(o0, s0.w, w3);
        fma4(o1, s1.x, w0); fma4(o1, s1.y, w1); fma4(o1, s1.z, w2); fma4(o1, s1.w, w3);
      }
      {
        size_t gr = (size_t)(bid * RPB + rg * 2) * D2 + c0;
        *(float4*)&p.h1[gr] = o0;
        *(float4*)&p.h1[gr + D2] = o1;
      }
      float* psum = sy;           // overlay (agg done)
      float* psq  = sy + 1024;
      *(float4*)&psum[rg * D2 + c0] =
          make_float4(o0.x + o1.x, o0.y + o1.y, o0.z + o1.z, o0.w + o1.w);
      *(float4*)&psq[rg * D2 + c0] =
          make_float4(o0.x * o0.x + o1.x * o1.x, o0.y * o0.y + o1.y * o1.y,
                      o0.z * o0.z + o1.z * o1.z, o0.w * o0.w + o1.w * o1.w);
      __syncthreads();
      if (tid < D2) {
        float s = 0.f, q = 0.f;
#pragma unroll
        for (int g = 0; g < 8; ++g) { s += psum[g * D2 + tid]; q += psq[g * D2 + tid]; }
        p.p1s[tid * GB + bid] = s;   // [channel][chunk]
        p.p1q[tid * GB + bid] = q;
      }
    }
    grid.sync();

    // ================= d phase: BN1+ReLU + MLP2 -> h2(x), p2 =================
    {
      float* sW2 = smem;
      float* sh1 = smem + 8192;       // stride 132
      float* sS  = smem + 10304;
      float* sB  = smem + 10432;
      float* sredD = smem + 10560;
      float* pstat = smem + 10816;    // [0..1024) sum, [1024..2048) sq

      for (int i = tid; i < D2 * DD; i += 256) sW2[i] = p.W2[l * D2 * DD + i];
      {
        int c = tid & 127;
        const float* pp = (tid < 128) ? p.p1s : p.p1q;
        const float4* p4 = (const float4*)(pp + c * GB);
        float s = 0.f;
#pragma unroll 8
        for (int g = 0; g < 64; ++g) { float4 v4 = p4[g]; s += v4.x + v4.y + v4.z + v4.w; }
        sredD[tid] = s;
      }
      __syncthreads();
      if (tid < 128) {
        float mean = sredD[tid] * (1.f / RTOT);
        float var = fmaf(-mean, mean, sredD[tid + 128] * (1.f / RTOT));
        float sc = p.g1[l * D2 + tid] * rsqrtf(var + 1e-5f);
        sS[tid] = sc;
        sB[tid] = fmaf(-mean, sc, p.be1[l * D2 + tid]);
      }
      __syncthreads();
      const float4* h14 = (const float4*)(p.h1 + (size_t)bid * RPB * D2);
      for (int i = tid; i < RPB * D2 / 4; i += 256) {
        float4 v = h14[i];
        int lr = i >> 5, c = (i & 31) * 4;
        v.x = fmaxf(fmaf(v.x, sS[c + 0], sB[c + 0]), 0.f);
        v.y = fmaxf(fmaf(v.y, sS[c + 1], sB[c + 1]), 0.f);
        v.z = fmaxf(fmaf(v.z, sS[c + 2], sB[c + 2]), 0.f);
        v.w = fmaxf(fmaf(v.w, sS[c + 3], sB[c + 3]), 0.f);
        *(float4*)&sh1[lr * 132 + c] = v;
      }
      __syncthreads();

      // MLP2: 16x64 tile, thread = 1 row x 4 cols
      int rg2 = tid >> 4, c2 = (tid & 15) * 4;
      float4 o = *(const float4*)&p.b2[l * DD + c2];
      for (int c = 0; c < D2; c += 4) {
        float4 s  = *(const float4*)&sh1[rg2 * 132 + c];
        float4 w0 = *(const float4*)&sW2[(c + 0) * DD + c2];
        float4 w1 = *(const float4*)&sW2[(c + 1) * DD + c2];
        float4 w2 = *(const float4*)&sW2[(c + 2) * DD + c2];
        float4 w3 = *(const float4*)&sW2[(c + 3) * DD + c2];
        fma4(o, s.x, w0); fma4(o, s.y, w1); fma4(o, s.z, w2); fma4(o, s.w, w3);
      }
      *(float4*)&p.x[(size_t)(bid * RPB + rg2) * DD + c2] = o;   // raw h2
      *(float4*)&pstat[rg2 * DD + c2] = o;
      *(float4*)&pstat[1024 + rg2 * DD + c2] =
          make_float4(o.x * o.x, o.y * o.y, o.z * o.z, o.w * o.w);
      __syncthreads();
      if (tid < DD) {
        float s = 0.f, q = 0.f;
#pragma unroll
        for (int g = 0; g < RPB; ++g) { s += pstat[g * DD + tid]; q += pstat[1024 + g * DD + tid]; }
        p.p2s[tid * GB + bid] = s;
        p.p2q[tid * GB + bid] = q;
      }
    }
    grid.sync();
  }

  // ================= final BN2 (no relu) -> out =================
  {
    float* sS2 = smem;
    float* sB2 = smem + 64;
    float* sred = smem + 128;
    int c = tid & 63, st = (tid >> 6) & 1, hf = tid >> 7;
    const float* pp = st ? p.p2q : p.p2s;
    const float4* p4 = (const float4*)(pp + c * GB + hf * 128);
    float s = 0.f;
#pragma unroll 8
    for (int g = 0; g < 32; ++g) { float4 v4 = p4[g]; s += v4.x + v4.y + v4.z + v4.w; }
    sred[tid] = s;
    __syncthreads();
    if (tid < 64) {
      float s1 = sred[tid] + sred[128 + tid];
      float q1 = sred[64 + tid] + sred[192 + tid];
      float mean = s1 * (1.f / RTOT);
      float var = fmaf(-mean, mean, q1 * (1.f / RTOT));
      float sc = p.gbn[2 * DD + tid] * rsqrtf(var + 1e-5f);
      sS2[tid] = sc;
      sB2[tid] = fmaf(-mean, sc, p.bbn[2 * DD + tid]);
    }
    __syncthreads();
#pragma unroll
    for (int k = 0; k < 4; ++k) {
      int idx = bid * 1024 + k * 256 + tid;
      p.out[idx] = fmaf(p.x[idx], sS2[idx & 63], sB2[idx & 63]);
    }
  }
}

extern "C" void kernel_launch(void* const* d_in, const int* in_sizes, int n_in,
                              void* d_out, int out_size, void* d_ws, size_t ws_size,
                              hipStream_t stream) {
  Params prm;
  prm.fea  = (const float*)d_in[0];
  prm.adj  = (const float*)d_in[1];
  prm.encW = (const float*)d_in[2];
  prm.encb = (const float*)d_in[3];
  prm.bondW= (const float*)d_in[4];
  prm.eps  = (const float*)d_in[5];
  prm.W1   = (const float*)d_in[6];
  prm.b1   = (const float*)d_in[7];
  prm.g1   = (const float*)d_in[8];
  prm.be1  = (const float*)d_in[9];
  prm.W2   = (const float*)d_in[10];
  prm.b2   = (const float*)d_in[11];
  prm.gbn  = (const float*)d_in[12];
  prm.bbn  = (const float*)d_in[13];
  prm.out  = (float*)d_out;
  float* ws = (float*)d_ws;
  prm.x   = ws;                 // 262144 floats
  prm.h1  = ws + 262144;        // 524288 floats
  prm.p1s = ws + 786432;        // 32768
  prm.p1q = prm.p1s + 32768;    // 32768
  prm.p2s = prm.p1q + 32768;    // 16384
  prm.p2q = prm.p2s + 16384;    // 16384

  void* args[] = { &prm };
  hipLaunchCooperativeKernel((const void*)fused, dim3(GB), dim3(256), args, 0, stream);
}

// Round 5
// 115.396 us; speedup vs baseline: 2.7847x; 2.7847x over previous
//
#include <hip/hip_runtime.h>

#define NN 256
#define DIN 32
#define DD 64
#define D2 128
#define RTOT 4096      // BB*NN rows
#define GB 256         // blocks for bc/d/fin kernels (= stat chunks)
#define RPB 16         // rows per block
#define JC 64          // j-chunk for agg

__device__ __forceinline__ void fma4(float4& o, float s, const float4& w) {
  o.x = fmaf(s, w.x, o.x);
  o.y = fmaf(s, w.y, o.y);
  o.z = fmaf(s, w.z, o.z);
  o.w = fmaf(s, w.w, o.w);
}

// x[r,c] = fea[r,:] @ encW + encb
__global__ __launch_bounds__(256) void enc_kernel(
    const float* __restrict__ fea, const float* __restrict__ W,
    const float* __restrict__ bias, float* __restrict__ x) {
  int g = blockIdx.x * 256 + threadIdx.x;   // 1024 blocks
  int r = g >> 6, c = g & 63;
  const float* fr = fea + r * DIN;
  float acc = bias[c];
#pragma unroll
  for (int k = 0; k < DIN; ++k) acc = fmaf(fr[k], W[k * DD + c], acc);
  x[g] = acc;
}

// Per layer: [optional prev BN2 affine+relu] -> sparse agg -> h -> MLP1 -> h1 + BN1 partials
__global__ __launch_bounds__(256) void bc_kernel(
    const float* __restrict__ adj, const float* __restrict__ x,
    const float* __restrict__ bondW, const float* __restrict__ epsp,
    const float* __restrict__ W1, const float* __restrict__ b1,
    const float* __restrict__ gbnp, const float* __restrict__ bbnp,  // prev-layer slices
    const float* __restrict__ p2s, const float* __restrict__ p2q,
    int apply_bn,
    float* __restrict__ h1, float* __restrict__ p1s, float* __restrict__ p1q) {
  __shared__ float sW1[DD * D2];      // 32 KB
  __shared__ float sy[JC * DD];       // 16 KB (reused as pst after agg)
  __shared__ float sadj[RPB * JC];    // 4 KB
  __shared__ float sh[RPB * DD];      // 4 KB
  __shared__ float sbw[DD];
  __shared__ float sS2[DD], sB2[DD];
  __shared__ float sred[256];
  int tid = threadIdx.x, bid = blockIdx.x;
  int lane = tid & 63, wv = tid >> 6;
  int b = bid >> 4;            // batch
  int r0 = (bid & 15) * RPB;   // row offset within batch

  {
    const float4* w4 = (const float4*)W1;
    float4* s4 = (float4*)sW1;
#pragma unroll
    for (int i = 0; i < 8; ++i) s4[tid + i * 256] = w4[tid + i * 256];
  }
  if (tid < DD) sbw[tid] = bondW[tid];
  if (apply_bn) {
    // previous layer's BN2 affine from p2 partial stats [channel][chunk]
    int c = tid & 63, st = (tid >> 6) & 1, hf = tid >> 7;
    const float* pp = st ? p2q : p2s;
    const float4* p4 = (const float4*)(pp + c * GB + hf * 128);
    float s = 0.f;
#pragma unroll 8
    for (int g = 0; g < 32; ++g) { float4 v4 = p4[g]; s += v4.x + v4.y + v4.z + v4.w; }
    sred[tid] = s;
    __syncthreads();
    if (tid < 64) {
      float s1 = sred[tid] + sred[128 + tid];
      float q1 = sred[64 + tid] + sred[192 + tid];
      float mean = s1 * (1.f / RTOT);
      float var = fmaf(-mean, mean, q1 * (1.f / RTOT));
      float sc = gbnp[tid] * rsqrtf(var + 1e-5f);
      sS2[tid] = sc;
      sB2[tid] = fmaf(-mean, sc, bbnp[tid]);
    }
  }

  float acc[4] = {0.f, 0.f, 0.f, 0.f};
  const float* xsrc = x + (size_t)b * NN * DD;
  const float* adjb = adj + ((size_t)b * NN + r0) * NN;

  for (int jc = 0; jc < NN; jc += JC) {
    __syncthreads();   // protects sy/sadj reuse; first iter fences staging/affine above
    const float4* src4 = (const float4*)(xsrc + jc * DD);
#pragma unroll
    for (int ii = 0; ii < 4; ++ii) {
      int i = tid + ii * 256;
      float4 v = src4[i];
      int d0 = (i & 15) * 4;
      if (apply_bn) {
        v.x = fmaxf(fmaf(v.x, sS2[d0 + 0], sB2[d0 + 0]), 0.f);
        v.y = fmaxf(fmaf(v.y, sS2[d0 + 1], sB2[d0 + 1]), 0.f);
        v.z = fmaxf(fmaf(v.z, sS2[d0 + 2], sB2[d0 + 2]), 0.f);
        v.w = fmaxf(fmaf(v.w, sS2[d0 + 3], sB2[d0 + 3]), 0.f);
      }
      v.x = fmaxf(v.x + sbw[d0 + 0], 0.f);
      v.y = fmaxf(v.y + sbw[d0 + 1], 0.f);
      v.z = fmaxf(v.z + sbw[d0 + 2], 0.f);
      v.w = fmaxf(v.w + sbw[d0 + 3], 0.f);
      ((float4*)sy)[i] = v;
    }
    {
      int lr = tid >> 4, c4 = (tid & 15) * 4;
      *(float4*)&sadj[lr * JC + c4] =
          *(const float4*)(adjb + (size_t)lr * NN + jc + c4);
    }
    __syncthreads();
    // ballot-compacted accumulate, 8 independent LDS loads per wait
    unsigned long long m[4];
#pragma unroll
    for (int k = 0; k < 4; ++k)
      m[k] = __ballot(sadj[(wv * 4 + k) * JC + lane] != 0.f);
    while (m[0] | m[1] | m[2] | m[3]) {
      float v[8];
      bool hb[8];
#pragma unroll
      for (int k = 0; k < 4; ++k) {
        bool b0 = m[k] != 0ull;
        int j0 = b0 ? __builtin_ctzll(m[k]) : 0;
        m[k] &= m[k] - 1;
        bool b1 = m[k] != 0ull;
        int j1 = b1 ? __builtin_ctzll(m[k]) : 0;
        m[k] &= m[k] - 1;
        hb[2 * k] = b0; hb[2 * k + 1] = b1;
        v[2 * k] = sy[j0 * DD + lane];
        v[2 * k + 1] = sy[j1 * DD + lane];
      }
#pragma unroll
      for (int k = 0; k < 4; ++k)
        acc[k] += (hb[2 * k] ? v[2 * k] : 0.f) + (hb[2 * k + 1] ? v[2 * k + 1] : 0.f);
    }
  }

  float epv = 1.f + epsp[0];
#pragma unroll
  for (int k = 0; k < 4; ++k) {
    int lr = wv * 4 + k;
    float raw = x[((size_t)b * NN + r0 + lr) * DD + lane];
    float xv = apply_bn ? fmaxf(fmaf(raw, sS2[lane], sB2[lane]), 0.f) : raw;
    sh[lr * DD + lane] = fmaf(epv, xv, acc[k]);
  }
  __syncthreads();

  // MLP1: 16x128 tile; 128 threads, each 4 rows x 4 cols
  float* pssum = sy;          // overlay: 4*128 floats
  float* pssq  = sy + 512;
  if (tid < 128) {
    int rg = tid >> 5;          // 4 row-groups of 4
    int c0 = (tid & 31) * 4;    // 128 cols
    float4 bv = *(const float4*)&b1[c0];
    float4 o0 = bv, o1 = bv, o2 = bv, o3 = bv;
    for (int d = 0; d < DD; d += 4) {
      float4 s0 = *(const float4*)&sh[(rg * 4 + 0) * DD + d];
      float4 s1 = *(const float4*)&sh[(rg * 4 + 1) * DD + d];
      float4 s2 = *(const float4*)&sh[(rg * 4 + 2) * DD + d];
      float4 s3 = *(const float4*)&sh[(rg * 4 + 3) * DD + d];
      float4 w0 = *(const float4*)&sW1[(d + 0) * D2 + c0];
      float4 w1 = *(const float4*)&sW1[(d + 1) * D2 + c0];
      float4 w2 = *(const float4*)&sW1[(d + 2) * D2 + c0];
      float4 w3 = *(const float4*)&sW1[(d + 3) * D2 + c0];
      fma4(o0, s0.x, w0); fma4(o0, s0.y, w1); fma4(o0, s0.z, w2); fma4(o0, s0.w, w3);
      fma4(o1, s1.x, w0); fma4(o1, s1.y, w1); fma4(o1, s1.z, w2); fma4(o1, s1.w, w3);
      fma4(o2, s2.x, w0); fma4(o2, s2.y, w1); fma4(o2, s2.z, w2); fma4(o2, s2.w, w3);
      fma4(o3, s3.x, w0); fma4(o3, s3.y, w1); fma4(o3, s3.z, w2); fma4(o3, s3.w, w3);
    }
    size_t gr = (size_t)(bid * RPB + rg * 4) * D2 + c0;
    *(float4*)&h1[gr] = o0;
    *(float4*)&h1[gr + D2] = o1;
    *(float4*)&h1[gr + 2 * D2] = o2;
    *(float4*)&h1[gr + 3 * D2] = o3;
    *(float4*)&pssum[rg * D2 + c0] =
        make_float4(o0.x + o1.x + o2.x + o3.x, o0.y + o1.y + o2.y + o3.y,
                    o0.z + o1.z + o2.z + o3.z, o0.w + o1.w + o2.w + o3.w);
    *(float4*)&pssq[rg * D2 + c0] = make_float4(
        o0.x * o0.x + o1.x * o1.x + o2.x * o2.x + o3.x * o3.x,
        o0.y * o0.y + o1.y * o1.y + o2.y * o2.y + o3.y * o3.y,
        o0.z * o0.z + o1.z * o1.z + o2.z * o2.z + o3.z * o3.z,
        o0.w * o0.w + o1.w * o1.w + o2.w * o2.w + o3.w * o3.w);
  }
  __syncthreads();
  if (tid < D2) {
    float s = 0.f, q = 0.f;
#pragma unroll
    for (int g = 0; g < 4; ++g) { s += pssum[g * D2 + tid]; q += pssq[g * D2 + tid]; }
    p1s[tid * GB + bid] = s;   // [channel][chunk]
    p1q[tid * GB + bid] = q;
  }
}

// Per layer: reduce BN1 stats -> BN+ReLU -> MLP2 -> raw h2 (into x) + BN2 partials
__global__ __launch_bounds__(256) void d_kernel(
    const float* __restrict__ h1, const float* __restrict__ W2,
    const float* __restrict__ b2, const float* __restrict__ g1,
    const float* __restrict__ be1, float* __restrict__ h2,
    const float* __restrict__ p1s, const float* __restrict__ p1q,
    float* __restrict__ p2s, float* __restrict__ p2q) {
  __shared__ float sW2[D2 * DD];          // 32 KB
  __shared__ float sh1[RPB][D2 + 4];      // padded
  __shared__ float sS[D2], sB[D2];
  __shared__ float sred[256];
  __shared__ float pst[2 * 4 * DD];       // 2 KB
  int tid = threadIdx.x, bid = blockIdx.x;

  {
    const float4* w4 = (const float4*)W2;
    float4* s4 = (float4*)sW2;
#pragma unroll
    for (int i = 0; i < 8; ++i) s4[tid + i * 256] = w4[tid + i * 256];
  }
  {
    int c = tid & 127;
    const float* pp = (tid < 128) ? p1s : p1q;
    const float4* p4 = (const float4*)(pp + c * GB);
    float s = 0.f;
#pragma unroll 8
    for (int g = 0; g < 64; ++g) { float4 v4 = p4[g]; s += v4.x + v4.y + v4.z + v4.w; }
    sred[tid] = s;
  }
  __syncthreads();
  if (tid < 128) {
    float mean = sred[tid] * (1.f / RTOT);
    float var = fmaf(-mean, mean, sred[tid + 128] * (1.f / RTOT));
    float sc = g1[tid] * rsqrtf(var + 1e-5f);
    sS[tid] = sc;
    sB[tid] = fmaf(-mean, sc, be1[tid]);
  }
  __syncthreads();
  {
    const float4* h14 = (const float4*)(h1 + (size_t)bid * RPB * D2);
#pragma unroll
    for (int ii = 0; ii < 2; ++ii) {
      int i = tid + ii * 256;
      float4 v = h14[i];
      int lr = i >> 5, c = (i & 31) * 4;
      v.x = fmaxf(fmaf(v.x, sS[c + 0], sB[c + 0]), 0.f);
      v.y = fmaxf(fmaf(v.y, sS[c + 1], sB[c + 1]), 0.f);
      v.z = fmaxf(fmaf(v.z, sS[c + 2], sB[c + 2]), 0.f);
      v.w = fmaxf(fmaf(v.w, sS[c + 3], sB[c + 3]), 0.f);
      *(float4*)&sh1[lr][c] = v;
    }
  }
  __syncthreads();

  // MLP2: 16x64 tile; 64 threads, each 4 rows x 4 cols
  float* pssum = pst;
  float* pssq  = pst + 4 * DD;
  if (tid < 64) {
    int rg = tid >> 4;          // 4 row-groups of 4
    int c0 = (tid & 15) * 4;    // 64 cols
    float4 bv = *(const float4*)&b2[c0];
    float4 o0 = bv, o1 = bv, o2 = bv, o3 = bv;
    for (int c = 0; c < D2; c += 4) {
      float4 s0 = *(const float4*)&sh1[rg * 4 + 0][c];
      float4 s1 = *(const float4*)&sh1[rg * 4 + 1][c];
      float4 s2 = *(const float4*)&sh1[rg * 4 + 2][c];
      float4 s3 = *(const float4*)&sh1[rg * 4 + 3][c];
      float4 w0 = *(const float4*)&sW2[(c + 0) * DD + c0];
      float4 w1 = *(const float4*)&sW2[(c + 1) * DD + c0];
      float4 w2 = *(const float4*)&sW2[(c + 2) * DD + c0];
      float4 w3 = *(const float4*)&sW2[(c + 3) * DD + c0];
      fma4(o0, s0.x, w0); fma4(o0, s0.y, w1); fma4(o0, s0.z, w2); fma4(o0, s0.w, w3);
      fma4(o1, s1.x, w0); fma4(o1, s1.y, w1); fma4(o1, s1.z, w2); fma4(o1, s1.w, w3);
      fma4(o2, s2.x, w0); fma4(o2, s2.y, w1); fma4(o2, s2.z, w2); fma4(o2, s2.w, w3);
      fma4(o3, s3.x, w0); fma4(o3, s3.y, w1); fma4(o3, s3.z, w2); fma4(o3, s3.w, w3);
    }
    size_t gr = (size_t)(bid * RPB + rg * 4) * DD + c0;
    *(float4*)&h2[gr] = o0;
    *(float4*)&h2[gr + DD] = o1;
    *(float4*)&h2[gr + 2 * DD] = o2;
    *(float4*)&h2[gr + 3 * DD] = o3;
    *(float4*)&pssum[rg * DD + c0] =
        make_float4(o0.x + o1.x + o2.x + o3.x, o0.y + o1.y + o2.y + o3.y,
                    o0.z + o1.z + o2.z + o3.z, o0.w + o1.w + o2.w + o3.w);
    *(float4*)&pssq[rg * DD + c0] = make_float4(
        o0.x * o0.x + o1.x * o1.x + o2.x * o2.x + o3.x * o3.x,
        o0.y * o0.y + o1.y * o1.y + o2.y * o2.y + o3.y * o3.y,
        o0.z * o0.z + o1.z * o1.z + o2.z * o2.z + o3.z * o3.z,
        o0.w * o0.w + o1.w * o1.w + o2.w * o2.w + o3.w * o3.w);
  }
  __syncthreads();
  if (tid < DD) {
    float s = 0.f, q = 0.f;
#pragma unroll
    for (int g = 0; g < 4; ++g) { s += pssum[g * DD + tid]; q += pssq[g * DD + tid]; }
    p2s[tid * GB + bid] = s;   // [channel][chunk]
    p2q[tid * GB + bid] = q;
  }
}

// Final: reduce BN2 stats -> BN (no relu) -> out
__global__ __launch_bounds__(256) void fin_kernel(
    const float* __restrict__ h2, const float* __restrict__ gbn,
    const float* __restrict__ bbn, const float* __restrict__ p2s,
    const float* __restrict__ p2q, float* __restrict__ outp) {
  __shared__ float sS2[DD], sB2[DD], sred[256];
  int tid = threadIdx.x, bid = blockIdx.x;
  {
    int c = tid & 63, st = (tid >> 6) & 1, hf = tid >> 7;
    const float* pp = st ? p2q : p2s;
    const float4* p4 = (const float4*)(pp + c * GB + hf * 128);
    float s = 0.f;
#pragma unroll 8
    for (int g = 0; g < 32; ++g) { float4 v4 = p4[g]; s += v4.x + v4.y + v4.z + v4.w; }
    sred[tid] = s;
  }
  __syncthreads();
  if (tid < 64) {
    float s1 = sred[tid] + sred[128 + tid];
    float q1 = sred[64 + tid] + sred[192 + tid];
    float mean = s1 * (1.f / RTOT);
    float var = fmaf(-mean, mean, q1 * (1.f / RTOT));
    float sc = gbn[tid] * rsqrtf(var + 1e-5f);
    sS2[tid] = sc;
    sB2[tid] = fmaf(-mean, sc, bbn[tid]);
  }
  __syncthreads();
#pragma unroll
  for (int k = 0; k < 4; ++k) {
    int idx = bid * 1024 + k * 256 + tid;
    outp[idx] = fmaf(h2[idx], sS2[idx & 63], sB2[idx & 63]);
  }
}

extern "C" void kernel_launch(void* const* d_in, const int* in_sizes, int n_in,
                              void* d_out, int out_size, void* d_ws, size_t ws_size,
                              hipStream_t stream) {
  const float* fea  = (const float*)d_in[0];
  const float* adj  = (const float*)d_in[1];
  const float* encW = (const float*)d_in[2];
  const float* encb = (const float*)d_in[3];
  const float* bondW= (const float*)d_in[4];
  const float* eps  = (const float*)d_in[5];
  const float* W1   = (const float*)d_in[6];
  const float* b1   = (const float*)d_in[7];
  const float* g1   = (const float*)d_in[8];
  const float* be1  = (const float*)d_in[9];
  const float* W2   = (const float*)d_in[10];
  const float* b2   = (const float*)d_in[11];
  const float* gbn  = (const float*)d_in[12];
  const float* bbn  = (const float*)d_in[13];
  float* out = (float*)d_out;
  float* ws  = (float*)d_ws;

  float* x   = ws;                 // 262144 floats (enc out / raw h2)
  float* h1  = ws + 262144;        // 524288 floats
  float* p1s = ws + 786432;        // 32768
  float* p1q = p1s + 32768;        // 32768
  float* p2s = p1q + 32768;        // 16384
  float* p2q = p2s + 16384;        // 16384

  enc_kernel<<<1024, 256, 0, stream>>>(fea, encW, encb, x);
  for (int l = 0; l < 3; ++l) {
    bc_kernel<<<GB, 256, 0, stream>>>(
        adj, x, bondW + l * DD, eps + l, W1 + l * DD * D2, b1 + l * D2,
        l ? gbn + (l - 1) * DD : gbn, l ? bbn + (l - 1) * DD : bbn,
        p2s, p2q, l > 0 ? 1 : 0, h1, p1s, p1q);
    d_kernel<<<GB, 256, 0, stream>>>(h1, W2 + l * D2 * DD, b2 + l * DD,
                                     g1 + l * D2, be1 + l * D2, x,
                                     p1s, p1q, p2s, p2q);
  }
  fin_kernel<<<GB, 256, 0, stream>>>(x, gbn + 2 * DD, bbn + 2 * DD, p2s, p2q, out);
}